// Round 1
// baseline (64.655 us; speedup 1.0000x reference)
//
#include <hip/hip_runtime.h>

// CRPS loss, mean reduction.
// forecasts: (N=20, M) f32 where M = B*C*D*H*W; target: (M,) f32; out: scalar f32.
// crps(m) = (1/N) sum_i |x_i - y| - (1/N^2) sum_{i<j} |x_i - x_j|
// out = mean_m crps(m)

constexpr int NS = 20;          // sample count (compile-time for full unroll)
constexpr int BLOCK = 256;

__global__ __launch_bounds__(BLOCK) void crps_partial_kernel(
    const float* __restrict__ forecasts,
    const float* __restrict__ target,
    float* __restrict__ partial,   // one float per block
    int M4)                        // M/4 (positions in float4 units)
{
    const int idx = blockIdx.x * BLOCK + threadIdx.x;
    float local = 0.0f;

    if (idx < M4) {
        const float4* __restrict__ f4 = reinterpret_cast<const float4*>(forecasts);
        const float4* __restrict__ t4 = reinterpret_cast<const float4*>(target);

        // Load 20 samples x 4 consecutive positions. Wave-coalesced: lane i
        // reads 16B at base + i*16 -> one 1KiB transaction per sample row.
        float x[4][NS];
        #pragma unroll
        for (int i = 0; i < NS; ++i) {
            float4 v = f4[(size_t)i * (size_t)M4 + idx];
            x[0][i] = v.x; x[1][i] = v.y; x[2][i] = v.z; x[3][i] = v.w;
        }
        float4 tv = t4[idx];
        float t[4] = {tv.x, tv.y, tv.z, tv.w};

        #pragma unroll
        for (int c = 0; c < 4; ++c) {
            float first = 0.0f;
            #pragma unroll
            for (int i = 0; i < NS; ++i)
                first += fabsf(x[c][i] - t[c]);
            float pair = 0.0f;
            #pragma unroll
            for (int i = 0; i < NS; ++i)
                #pragma unroll
                for (int j = i + 1; j < NS; ++j)
                    pair += fabsf(x[c][i] - x[c][j]);
            local += first * (1.0f / NS) - pair * (1.0f / (NS * NS));
        }
    }

    // Wave (64-lane) shuffle reduce, then cross-wave via LDS.
    #pragma unroll
    for (int off = 32; off > 0; off >>= 1)
        local += __shfl_down(local, off, 64);

    __shared__ float wsum[BLOCK / 64];
    const int lane = threadIdx.x & 63;
    const int wid  = threadIdx.x >> 6;
    if (lane == 0) wsum[wid] = local;
    __syncthreads();
    if (threadIdx.x == 0) {
        float s = 0.0f;
        #pragma unroll
        for (int w = 0; w < BLOCK / 64; ++w) s += wsum[w];
        partial[blockIdx.x] = s;
    }
}

__global__ __launch_bounds__(BLOCK) void crps_final_kernel(
    const float* __restrict__ partial,
    int nblocks,
    float* __restrict__ out,
    float invM)
{
    // Deterministic: fixed per-thread accumulation order + fixed tree reduce.
    float s = 0.0f;
    for (int i = threadIdx.x; i < nblocks; i += BLOCK)
        s += partial[i];

    #pragma unroll
    for (int off = 32; off > 0; off >>= 1)
        s += __shfl_down(s, off, 64);

    __shared__ float wsum[BLOCK / 64];
    const int lane = threadIdx.x & 63;
    const int wid  = threadIdx.x >> 6;
    if (lane == 0) wsum[wid] = s;
    __syncthreads();
    if (threadIdx.x == 0) {
        float tot = 0.0f;
        #pragma unroll
        for (int w = 0; w < BLOCK / 64; ++w) tot += wsum[w];
        out[0] = tot * invM;
    }
}

extern "C" void kernel_launch(void* const* d_in, const int* in_sizes, int n_in,
                              void* d_out, int out_size, void* d_ws, size_t ws_size,
                              hipStream_t stream) {
    const float* forecasts = (const float*)d_in[0];
    const float* target    = (const float*)d_in[1];
    float* out = (float*)d_out;
    float* partial = (float*)d_ws;

    const int M  = in_sizes[1];          // B*C*D*H*W = 3,145,728
    const int M4 = M >> 2;               // divisible by 4 (W=256)
    const int nblocks = (M4 + BLOCK - 1) / BLOCK;   // 3072

    crps_partial_kernel<<<nblocks, BLOCK, 0, stream>>>(forecasts, target, partial, M4);
    crps_final_kernel<<<1, BLOCK, 0, stream>>>(partial, nblocks, out, 1.0f / (float)M);
}